// Round 1
// baseline (234.488 us; speedup 1.0000x reference)
//
#include <hip/hip_runtime.h>
#include <stdint.h>

// Problem constants
#define B_    8
#define S_    2048
#define HID_  1024
#define H_    16
#define DH_   64
#define M_    (B_ * S_)   // 16384 rows

using bf16x8 = __attribute__((ext_vector_type(8))) __bf16;
using bf16x4 = __attribute__((ext_vector_type(4))) __bf16;
using f32x4  = __attribute__((ext_vector_type(4))) float;

__device__ __forceinline__ void gload_lds16(const void* g, void* l) {
  __builtin_amdgcn_global_load_lds(
      (const __attribute__((address_space(1))) void*)g,
      (__attribute__((address_space(3))) void*)l, 16, 0, 0);
}

// ---------------- prep: cast hidden_states fp32 -> bf16 ----------------
__global__ void cast_hs(const float* __restrict__ hs, __bf16* __restrict__ out, int n8) {
  int i = blockIdx.x * blockDim.x + threadIdx.x;
  int stride = gridDim.x * blockDim.x;
  for (; i < n8; i += stride) {
    const float4* p = (const float4*)(hs + (size_t)i * 8);
    float4 a = p[0], c = p[1];
    bf16x8 v;
    v[0] = (__bf16)a.x; v[1] = (__bf16)a.y; v[2] = (__bf16)a.z; v[3] = (__bf16)a.w;
    v[4] = (__bf16)c.x; v[5] = (__bf16)c.y; v[6] = (__bf16)c.z; v[7] = (__bf16)c.w;
    *(bf16x8*)(out + (size_t)i * 8) = v;
  }
}

// ---------------- prep: W [k][n] -> Wt [w][n][k] bf16 ----------------
__global__ void transpose_w(const float* __restrict__ Wq, const float* __restrict__ Wk,
                            const float* __restrict__ Wv, __bf16* __restrict__ Wt) {
  __shared__ float tile[32][33];
  int w = blockIdx.z;
  const float* W = (w == 0) ? Wq : (w == 1) ? Wk : Wv;
  int k0 = blockIdx.x * 32, n0 = blockIdx.y * 32;
  int tx = threadIdx.x, ty = threadIdx.y;
#pragma unroll
  for (int i = 0; i < 4; ++i)
    tile[ty * 4 + i][tx] = W[(size_t)(k0 + ty * 4 + i) * HID_ + n0 + tx];
  __syncthreads();
#pragma unroll
  for (int i = 0; i < 4; ++i)
    Wt[(size_t)w * HID_ * HID_ + (size_t)(n0 + ty * 4 + i) * HID_ + k0 + tx] =
        (__bf16)tile[tx][ty * 4 + i];
}

// ---------------- prep: per-row validity + per-batch count ----------------
__global__ void mask_prep(const int* __restrict__ mask, float* __restrict__ validf,
                          float* __restrict__ counts) {
  __shared__ float red[256];
  int b = blockIdx.x;
  float cnt = 0.f;
  for (int s = threadIdx.x; s < S_; s += 256) {
    float v = (mask[b * S_ + s] == 0) ? 1.f : 0.f;
    validf[b * S_ + s] = v;
    cnt += v;
  }
  red[threadIdx.x] = cnt;
  __syncthreads();
  for (int off = 128; off > 0; off >>= 1) {
    if (threadIdx.x < off) red[threadIdx.x] += red[threadIdx.x + off];
    __syncthreads();
  }
  if (threadIdx.x == 0) counts[b] = red[0];
}

// ---------------- QKV GEMM, 128x128 tile (m97 structure), fused epilogue ----
// C = hs_bf16 @ W^T-layout, + bias, * mask, l2norm (q,k) or /count (v).
// q -> natural [row][1024] bf16; k,v -> transposed [bh][dh][S] bf16.
__global__ __launch_bounds__(256, 2) void qkv_gemm(
    const __bf16* __restrict__ hsb, const __bf16* __restrict__ Wt,
    const float* __restrict__ biasq, const float* __restrict__ biask,
    const float* __restrict__ biasv, const float* __restrict__ validf,
    const float* __restrict__ counts, __bf16* __restrict__ qn,
    __bf16* __restrict__ kT, __bf16* __restrict__ vT) {
  __shared__ __bf16 As[128 * 64];
  __shared__ __bf16 Bs[128 * 64];

  // XCD-aware swizzle (3072 % 8 == 0 -> bijective)
  int nwg = gridDim.x;
  int bid = blockIdx.x;
  int swz = (bid & 7) * (nwg >> 3) + (bid >> 3);
  int tm = swz & 127;          // 128 m-tiles
  int tn = (swz >> 7) & 7;     // 8 n-tiles
  int w  = swz >> 10;          // weight 0..2

  int tid = threadIdx.x;
  int lane = tid & 63, wid = tid >> 6;
  int g = lane >> 4, lr = lane & 15;
  int wr = wid >> 1, wc = wid & 1;

  const __bf16* Bsrc = Wt + (size_t)w * HID_ * HID_;
  int m0 = tm * 128, n0 = tn * 128;

  f32x4 acc[4][4] = {};

  for (int kt = 0; kt < HID_; kt += 64) {
#pragma unroll
    for (int j = 0; j < 4; ++j) {
      int seg = tid + j * 256;
      int row = seg >> 3, col = (seg & 7) * 8;
      gload_lds16(hsb + (size_t)(m0 + row) * HID_ + kt + col, (void*)(As + seg * 8));
      gload_lds16(Bsrc + (size_t)(n0 + row) * HID_ + kt + col, (void*)(Bs + seg * 8));
    }
    __syncthreads();
#pragma unroll
    for (int kk = 0; kk < 64; kk += 32) {
      bf16x8 fa[4], fb[4];
#pragma unroll
      for (int m = 0; m < 4; ++m)
        fa[m] = *(const bf16x8*)(As + (wr * 64 + m * 16 + lr) * 64 + kk + g * 8);
#pragma unroll
      for (int n = 0; n < 4; ++n)
        fb[n] = *(const bf16x8*)(Bs + (wc * 64 + n * 16 + lr) * 64 + kk + g * 8);
#pragma unroll
      for (int m = 0; m < 4; ++m)
#pragma unroll
        for (int n = 0; n < 4; ++n)
          acc[m][n] = __builtin_amdgcn_mfma_f32_16x16x32_bf16(fa[m], fb[n], acc[m][n], 0, 0, 0);
    }
    __syncthreads();
  }

  // ---- fused epilogue ----
  const float* bias = (w == 0) ? biasq : (w == 1) ? biask : biasv;
  float bb[4];
#pragma unroll
  for (int n = 0; n < 4; ++n) bb[n] = bias[n0 + wc * 64 + n * 16 + lr];

  int batch = m0 >> 11;             // 128-row tile never crosses batch
  float invcnt = 1.0f / counts[batch];
  int h = tn * 2 + wc;              // head owned by this wave

#pragma unroll
  for (int m = 0; m < 4; ++m) {
    int rbase = m0 + wr * 64 + m * 16 + g * 4;
    float vld[4];
#pragma unroll
    for (int j = 0; j < 4; ++j) vld[j] = validf[rbase + j];
    float ss[4] = {0.f, 0.f, 0.f, 0.f};
#pragma unroll
    for (int n = 0; n < 4; ++n)
#pragma unroll
      for (int j = 0; j < 4; ++j) {
        float x = (acc[m][n][j] + bb[n]) * vld[j];
        acc[m][n][j] = x;
        ss[j] += x * x;
      }
    float sc[4];
#pragma unroll
    for (int j = 0; j < 4; ++j) {
      float s = ss[j];
      s += __shfl_xor(s, 1);
      s += __shfl_xor(s, 2);
      s += __shfl_xor(s, 4);
      s += __shfl_xor(s, 8);   // reduce over the 16 lanes holding this row's 64 cols
      if (w == 2) sc[j] = vld[j] * invcnt;
      else        sc[j] = 1.0f / fmaxf(sqrtf(s), 1e-12f);
    }
    if (w == 0) {
#pragma unroll
      for (int n = 0; n < 4; ++n) {
        int c = n0 + wc * 64 + n * 16 + lr;
#pragma unroll
        for (int j = 0; j < 4; ++j)
          qn[(size_t)(rbase + j) * HID_ + c] = (__bf16)(acc[m][n][j] * sc[j]);
      }
    } else {
      __bf16* dst = (w == 1) ? kT : vT;
      int sbase = rbase & (S_ - 1);
#pragma unroll
      for (int n = 0; n < 4; ++n) {
        int d = n * 16 + lr;
        bf16x4 pk;
#pragma unroll
        for (int j = 0; j < 4; ++j) pk[j] = (__bf16)(acc[m][n][j] * sc[j]);
        *(bf16x4*)(dst + (size_t)((batch * H_ + h) * DH_ + d) * S_ + sbase) = pk;
      }
    }
  }
}

// ---------------- kv phase: vk[bh][d][e] = sum_s v[s,d]*k[s,e] ----------------
__global__ __launch_bounds__(256) void kv_gemm(const __bf16* __restrict__ kT,
                                               const __bf16* __restrict__ vT,
                                               __bf16* __restrict__ vk) {
  __shared__ __align__(16) char smem[65536];
  __bf16* kbuf = (__bf16*)smem;              // [64][256]
  __bf16* vbuf = (__bf16*)(smem + 32768);    // [64][256]

  int bh = blockIdx.x;
  int tid = threadIdx.x, lane = tid & 63, wid = tid >> 6;
  int g = lane >> 4, lr = lane & 15;
  const __bf16* kb = kT + (size_t)bh * DH_ * S_;
  const __bf16* vb = vT + (size_t)bh * DH_ * S_;

  f32x4 acc[4][4] = {};

  for (int sc0 = 0; sc0 < S_; sc0 += 256) {
#pragma unroll
    for (int it = 0; it < 8; ++it) {
      int seg = tid + it * 256;
      int row = seg >> 5, col = (seg & 31) * 8;
      gload_lds16(kb + (size_t)row * S_ + sc0 + col, (void*)(kbuf + seg * 8));
      gload_lds16(vb + (size_t)row * S_ + sc0 + col, (void*)(vbuf + seg * 8));
    }
    __syncthreads();
    int sl = wid * 64;   // each wave owns a 64-wide K slice of the chunk
#pragma unroll
    for (int kk = 0; kk < 64; kk += 32) {
      bf16x8 fa[4], fb[4];
#pragma unroll
      for (int m = 0; m < 4; ++m)
        fa[m] = *(const bf16x8*)(vbuf + (m * 16 + lr) * 256 + sl + kk + g * 8);
#pragma unroll
      for (int n = 0; n < 4; ++n)
        fb[n] = *(const bf16x8*)(kbuf + (n * 16 + lr) * 256 + sl + kk + g * 8);
#pragma unroll
      for (int m = 0; m < 4; ++m)
#pragma unroll
        for (int n = 0; n < 4; ++n)
          acc[m][n] = __builtin_amdgcn_mfma_f32_16x16x32_bf16(fa[m], fb[n], acc[m][n], 0, 0, 0);
    }
    __syncthreads();
  }

  // cross-wave reduce through LDS (reuse staging space)
  float* red = (float*)smem;   // 4 x [64][64] fp32 = 64KB
#pragma unroll
  for (int m = 0; m < 4; ++m)
#pragma unroll
    for (int n = 0; n < 4; ++n)
#pragma unroll
      for (int j = 0; j < 4; ++j)
        red[wid * 4096 + (m * 16 + g * 4 + j) * 64 + n * 16 + lr] = acc[m][n][j];
  __syncthreads();
  for (int idx = tid; idx < 4096; idx += 256) {
    float s = red[idx] + red[4096 + idx] + red[8192 + idx] + red[12288 + idx];
    vk[(size_t)bh * 4096 + idx] = (__bf16)s;
  }
}

// ---------------- ctx phase: out[b,s,h*64+d] = sum_e q[s,e]*vk[d,e] ----------------
__global__ __launch_bounds__(256) void ctx_gemm(const __bf16* __restrict__ qn,
                                                const __bf16* __restrict__ vk,
                                                float* __restrict__ out) {
  __shared__ __align__(16) __bf16 qbuf[128 * 64];
  __shared__ __align__(16) __bf16 wbuf[64 * 64];

  int st = blockIdx.x;   // s-tile (16)
  int bh = blockIdx.y;   // 128
  int b = bh >> 4, h = bh & 15;
  int tid = threadIdx.x, lane = tid & 63, wid = tid >> 6;
  int g = lane >> 4, lr = lane & 15;
  int s0 = st * 128;

#pragma unroll
  for (int it = 0; it < 4; ++it) {
    int seg = tid + it * 256;
    int row = seg >> 3, col = (seg & 7) * 8;
    gload_lds16(qn + (size_t)(b * S_ + s0 + row) * HID_ + h * DH_ + col,
                (void*)(qbuf + seg * 8));
  }
#pragma unroll
  for (int it = 0; it < 2; ++it) {
    int seg = tid + it * 256;
    gload_lds16(vk + (size_t)bh * 4096 + seg * 8, (void*)(wbuf + seg * 8));
  }
  __syncthreads();

  f32x4 acc[2][4] = {};
#pragma unroll
  for (int kk = 0; kk < 64; kk += 32) {
    bf16x8 fa[2], fb[4];
#pragma unroll
    for (int m = 0; m < 2; ++m)
      fa[m] = *(const bf16x8*)(qbuf + (wid * 32 + m * 16 + lr) * 64 + kk + g * 8);
#pragma unroll
    for (int n = 0; n < 4; ++n)
      fb[n] = *(const bf16x8*)(wbuf + (n * 16 + lr) * 64 + kk + g * 8);
#pragma unroll
    for (int m = 0; m < 2; ++m)
#pragma unroll
      for (int n = 0; n < 4; ++n)
        acc[m][n] = __builtin_amdgcn_mfma_f32_16x16x32_bf16(fa[m], fb[n], acc[m][n], 0, 0, 0);
  }

#pragma unroll
  for (int m = 0; m < 2; ++m) {
    int rbase = s0 + wid * 32 + m * 16 + g * 4;
#pragma unroll
    for (int n = 0; n < 4; ++n) {
      int d = n * 16 + lr;
#pragma unroll
      for (int j = 0; j < 4; ++j)
        out[(size_t)(b * S_ + rbase + j) * HID_ + h * DH_ + d] = acc[m][n][j];
    }
  }
}

extern "C" void kernel_launch(void* const* d_in, const int* in_sizes, int n_in,
                              void* d_out, int out_size, void* d_ws, size_t ws_size,
                              hipStream_t stream) {
  const float* hs   = (const float*)d_in[0];
  const int*   mask = (const int*)d_in[1];
  const float* Wq   = (const float*)d_in[2];
  const float* bq   = (const float*)d_in[3];
  const float* Wk   = (const float*)d_in[4];
  const float* bk   = (const float*)d_in[5];
  const float* Wv   = (const float*)d_in[6];
  const float* bv   = (const float*)d_in[7];
  float* out = (float*)d_out;

  // ws layout (bytes): needs ~137.1 MB total
  char* ws = (char*)d_ws;
  __bf16* hsb    = (__bf16*)(ws);                           // 32 MB
  __bf16* Wt     = (__bf16*)(ws + (33554432));              // 6 MB
  __bf16* qn     = (__bf16*)(ws + (41943040));              // 32 MB
  __bf16* kT     = (__bf16*)(ws + (75497472));              // 32 MB
  __bf16* vT     = (__bf16*)(ws + (109051904));             // 32 MB
  __bf16* vk     = (__bf16*)(ws + (142606336));             // 1 MB
  float*  validf = (float*)(ws + (143654912));              // 64 KB
  float*  counts = (float*)(ws + (143654912) + 65536);      // 32 B

  cast_hs<<<2048, 256, 0, stream>>>(hs, hsb, (B_ * S_ * HID_) / 8);
  transpose_w<<<dim3(32, 32, 3), dim3(32, 8), 0, stream>>>(Wq, Wk, Wv, Wt);
  mask_prep<<<8, 256, 0, stream>>>(mask, validf, counts);
  qkv_gemm<<<3072, 256, 0, stream>>>(hsb, Wt, bq, bk, bv, validf, counts, qn, kT, vT);
  kv_gemm<<<128, 256, 0, stream>>>(kT, vT, vk);
  ctx_gemm<<<dim3(16, 128), 256, 0, stream>>>(qn, vk, out);
}

// Round 2
// 208.511 us; speedup vs baseline: 1.1246x; 1.1246x over previous
//
#include <hip/hip_runtime.h>
#include <stdint.h>

// Problem constants
#define B_    8
#define S_    2048
#define HID_  1024
#define H_    16
#define DH_   64
#define M_    (B_ * S_)   // 16384 rows

using bf16x8 = __attribute__((ext_vector_type(8))) __bf16;
using bf16x4 = __attribute__((ext_vector_type(4))) __bf16;
using f32x4  = __attribute__((ext_vector_type(4))) float;

__device__ __forceinline__ void gload_lds16(const void* g, void* l) {
  __builtin_amdgcn_global_load_lds(
      (const __attribute__((address_space(1))) void*)g,
      (__attribute__((address_space(3))) void*)l, 16, 0, 0);
}

// ---------------- prep: cast hidden_states fp32 -> bf16 ----------------
__global__ void cast_hs(const float* __restrict__ hs, __bf16* __restrict__ out, int n8) {
  int i = blockIdx.x * blockDim.x + threadIdx.x;
  int stride = gridDim.x * blockDim.x;
  for (; i < n8; i += stride) {
    const float4* p = (const float4*)(hs + (size_t)i * 8);
    float4 a = p[0], c = p[1];
    bf16x8 v;
    v[0] = (__bf16)a.x; v[1] = (__bf16)a.y; v[2] = (__bf16)a.z; v[3] = (__bf16)a.w;
    v[4] = (__bf16)c.x; v[5] = (__bf16)c.y; v[6] = (__bf16)c.z; v[7] = (__bf16)c.w;
    *(bf16x8*)(out + (size_t)i * 8) = v;
  }
}

// ---------------- prep: W [k][n] -> Wt [w][n][k] bf16 ----------------
__global__ void transpose_w(const float* __restrict__ Wq, const float* __restrict__ Wk,
                            const float* __restrict__ Wv, __bf16* __restrict__ Wt) {
  __shared__ float tile[32][33];
  int w = blockIdx.z;
  const float* W = (w == 0) ? Wq : (w == 1) ? Wk : Wv;
  int k0 = blockIdx.x * 32, n0 = blockIdx.y * 32;
  int tx = threadIdx.x, ty = threadIdx.y;
#pragma unroll
  for (int i = 0; i < 4; ++i)
    tile[ty * 4 + i][tx] = W[(size_t)(k0 + ty * 4 + i) * HID_ + n0 + tx];
  __syncthreads();
#pragma unroll
  for (int i = 0; i < 4; ++i)
    Wt[(size_t)w * HID_ * HID_ + (size_t)(n0 + ty * 4 + i) * HID_ + k0 + tx] =
        (__bf16)tile[tx][ty * 4 + i];
}

// ---------------- prep: per-row validity + per-batch count ----------------
__global__ void mask_prep(const int* __restrict__ mask, float* __restrict__ validf,
                          float* __restrict__ counts) {
  __shared__ float red[256];
  int b = blockIdx.x;
  float cnt = 0.f;
  for (int s = threadIdx.x; s < S_; s += 256) {
    float v = (mask[b * S_ + s] == 0) ? 1.f : 0.f;
    validf[b * S_ + s] = v;
    cnt += v;
  }
  red[threadIdx.x] = cnt;
  __syncthreads();
  for (int off = 128; off > 0; off >>= 1) {
    if (threadIdx.x < off) red[threadIdx.x] += red[threadIdx.x + off];
    __syncthreads();
  }
  if (threadIdx.x == 0) counts[b] = red[0];
}

// ============ QKV GEMM: 256x256 tile, BK=64, 8-wave, 8-phase (T2+T3+T4+T5) ===
// C = hs_bf16 @ Wt^T(stored [n][k]), fused bias/mask/l2norm or /count epilogue.
// Waves: 2(M) x 4(N). Per-wave C: two 64-row strips (mh-staggered) x 64 cols
// (= exactly one head). LDS: As/Bs [2 dbuf][2 half][128*64] bf16 = 128 KiB.
// Swizzle: LDS cell (row, colbyte cb) holds global col ((cb>>4)^(row&7))*8..+8
// (pre-swizzled global source; XOR'd ds_read).
// Stage schedule per group t: q1:(t+1).A1  q2:(t+1).B0  q3:(t+1).B1
//                             q4:(t+2).A0 + s_waitcnt vmcnt(2)
// Invariant at group-t start: tile t fully landed; (t+1).A0 (2 loads) in flight.
__global__ __launch_bounds__(512, 2) void qkv_gemm8(
    const __bf16* __restrict__ hsb, const __bf16* __restrict__ Wt,
    const float* __restrict__ biasq, const float* __restrict__ biask,
    const float* __restrict__ biasv, const float* __restrict__ validf,
    const float* __restrict__ counts, __bf16* __restrict__ qn,
    __bf16* __restrict__ kT, __bf16* __restrict__ vT) {
  __shared__ __bf16 As[2][2][128 * 64];   // [dbuf][m-half][row*64+col]
  __shared__ __bf16 Bs[2][2][128 * 64];   // [dbuf][n-half][row*64+col]

  // XCD-aware block order: each XCD gets 8 consecutive tm x all 12 (tn,w).
  int bid = blockIdx.x;
  int swz = (bid & 7) * 96 + (bid >> 3);       // 768 % 8 == 0 -> bijective
  int tm = swz / 12;
  int tnw = swz - tm * 12;
  int tn = tnw & 3;
  int w  = tnw >> 2;

  int tid = threadIdx.x;
  int lane = tid & 63, wid = tid >> 6;
  int lr = lane & 15, g = lane >> 4;
  int wr = wid >> 2, wcn = wid & 3;

  int m0 = tm * 256, n0 = tn * 256;
  const __bf16* Bsrc = Wt + (size_t)w * (HID_ * HID_);

  // staging constants (512 threads stage one 128x64 half = 2 x 16B each)
  int srow = tid >> 3;                              // row 0..63 (+64 for seg 1)
  int scol = ((tid & 7) ^ (srow & 7)) << 3;         // swizzled source col (elems)
  int soff = tid * 16;                              // LDS byte offset (+8192 seg 1)

  auto stA = [&](int t_, int ah) {
    const __bf16* s0 = hsb + (size_t)(m0 + ah * 128 + srow) * HID_ + t_ * 64 + scol;
    char* d = (char*)&As[t_ & 1][ah][0] + soff;
    gload_lds16(s0, d);
    gload_lds16(s0 + (size_t)64 * HID_, d + 8192);
  };
  auto stB = [&](int t_, int bh) {
    const __bf16* s0 = Bsrc + (size_t)(n0 + bh * 128 + srow) * HID_ + t_ * 64 + scol;
    char* d = (char*)&Bs[t_ & 1][bh][0] + soff;
    gload_lds16(s0, d);
    gload_lds16(s0 + (size_t)64 * HID_, d + 8192);
  };

  // ds_read constants
  int swz8 = (lr & 7) << 4;
  int arow = wr * 64 + lr;          // + mf*16
  int brow = (wcn & 1) * 64 + lr;   // + nf*16
  int bsel = wcn >> 1;

  f32x4 acc[8][4] = {};

#define PHASE(MH, KK, STAGE, VM)                                              \
  {                                                                           \
    bf16x8 fa[4], fb[4];                                                      \
    const char* abase = (const char*)&As[buf][MH][0];                         \
    const char* bbase = (const char*)&Bs[buf][bsel][0];                       \
    _Pragma("unroll")                                                         \
    for (int mf = 0; mf < 4; ++mf)                                            \
      fa[mf] = *(const bf16x8*)(abase + (arow + mf * 16) * 128 +              \
                                (((KK) * 64 + g * 16) ^ swz8));               \
    _Pragma("unroll")                                                         \
    for (int nf = 0; nf < 4; ++nf)                                            \
      fb[nf] = *(const bf16x8*)(bbase + (brow + nf * 16) * 128 +              \
                                (((KK) * 64 + g * 16) ^ swz8));               \
    STAGE;                                                                    \
    VM;                                                                       \
    __builtin_amdgcn_s_barrier();                                             \
    asm volatile("s_waitcnt lgkmcnt(0)" ::: "memory");                        \
    __builtin_amdgcn_sched_barrier(0);                                        \
    __builtin_amdgcn_s_setprio(1);                                            \
    _Pragma("unroll")                                                         \
    for (int mf = 0; mf < 4; ++mf)                                            \
      _Pragma("unroll")                                                       \
      for (int nf = 0; nf < 4; ++nf)                                          \
        acc[(MH) * 4 + mf][nf] = __builtin_amdgcn_mfma_f32_16x16x32_bf16(     \
            fa[mf], fb[nf], acc[(MH) * 4 + mf][nf], 0, 0, 0);                 \
    __builtin_amdgcn_s_setprio(0);                                            \
    __builtin_amdgcn_s_barrier();                                             \
  }

  // prologue: t0 complete + t1.A0 in flight (10 loads); drain t0 (8) -> vmcnt(2)
  stA(0, 0); stA(0, 1); stB(0, 0); stB(0, 1); stA(1, 0);
  asm volatile("s_waitcnt vmcnt(2)" ::: "memory");
  __builtin_amdgcn_s_barrier();

  for (int t = 0; t < 16; ++t) {
    int buf = t & 1;
    PHASE(0, 0, { if (t < 15) stA(t + 1, 1); }, {});
    PHASE(0, 1, { if (t < 15) stB(t + 1, 0); }, {});
    PHASE(1, 0, { if (t < 15) stB(t + 1, 1); }, {});
    PHASE(1, 1, { if (t < 14) stA(t + 2, 0); },
          {
            if (t < 14)       asm volatile("s_waitcnt vmcnt(2)" ::: "memory");
            else if (t == 14) asm volatile("s_waitcnt vmcnt(0)" ::: "memory");
          });
  }
#undef PHASE

  // ---- fused epilogue ----
  const float* bias = (w == 0) ? biasq : (w == 1) ? biask : biasv;
  float bb[4];
#pragma unroll
  for (int nf = 0; nf < 4; ++nf) bb[nf] = bias[n0 + wcn * 64 + nf * 16 + lr];

  int batch = m0 >> 11;              // 256-row tile never crosses batch (2048 rows)
  float invcnt = 1.0f / counts[batch];
  int h = tn * 4 + wcn;              // head owned by this wave

#pragma unroll
  for (int m = 0; m < 8; ++m) {
    int mh = m >> 2, mf = m & 3;
    int rbase = m0 + mh * 128 + wr * 64 + mf * 16 + g * 4;
    float vld[4];
#pragma unroll
    for (int j = 0; j < 4; ++j) vld[j] = validf[rbase + j];
    float ss[4] = {0.f, 0.f, 0.f, 0.f};
#pragma unroll
    for (int nf = 0; nf < 4; ++nf)
#pragma unroll
      for (int j = 0; j < 4; ++j) {
        float x = (acc[m][nf][j] + bb[nf]) * vld[j];
        acc[m][nf][j] = x;
        ss[j] += x * x;
      }
    float sc[4];
#pragma unroll
    for (int j = 0; j < 4; ++j) {
      float s = ss[j];
      s += __shfl_xor(s, 1);
      s += __shfl_xor(s, 2);
      s += __shfl_xor(s, 4);
      s += __shfl_xor(s, 8);   // reduce over 16 lanes holding this row's 64 cols
      if (w == 2) sc[j] = vld[j] * invcnt;
      else        sc[j] = 1.0f / fmaxf(sqrtf(s), 1e-12f);
    }
    if (w == 0) {
#pragma unroll
      for (int nf = 0; nf < 4; ++nf) {
        int c = n0 + wcn * 64 + nf * 16 + lr;
#pragma unroll
        for (int j = 0; j < 4; ++j)
          qn[(size_t)(rbase + j) * HID_ + c] = (__bf16)(acc[m][nf][j] * sc[j]);
      }
    } else {
      __bf16* dst = (w == 1) ? kT : vT;
      int sbase = rbase & (S_ - 1);
#pragma unroll
      for (int nf = 0; nf < 4; ++nf) {
        int d = nf * 16 + lr;
        bf16x4 pk;
#pragma unroll
        for (int j = 0; j < 4; ++j) pk[j] = (__bf16)(acc[m][nf][j] * sc[j]);
        *(bf16x4*)(dst + (size_t)((batch * H_ + h) * DH_ + d) * S_ + sbase) = pk;
      }
    }
  }
}

// ---------------- kv phase: vk[bh][d][e] = sum_s v[s,d]*k[s,e] ----------------
__global__ __launch_bounds__(256) void kv_gemm(const __bf16* __restrict__ kT,
                                               const __bf16* __restrict__ vT,
                                               __bf16* __restrict__ vk) {
  __shared__ __align__(16) char smem[65536];
  __bf16* kbuf = (__bf16*)smem;              // [64][256]
  __bf16* vbuf = (__bf16*)(smem + 32768);    // [64][256]

  int bh = blockIdx.x;
  int tid = threadIdx.x, lane = tid & 63, wid = tid >> 6;
  int g = lane >> 4, lr = lane & 15;
  const __bf16* kb = kT + (size_t)bh * DH_ * S_;
  const __bf16* vb = vT + (size_t)bh * DH_ * S_;

  f32x4 acc[4][4] = {};

  for (int sc0 = 0; sc0 < S_; sc0 += 256) {
#pragma unroll
    for (int it = 0; it < 8; ++it) {
      int seg = tid + it * 256;
      int row = seg >> 5, col = (seg & 31) * 8;
      gload_lds16(kb + (size_t)row * S_ + sc0 + col, (void*)(kbuf + seg * 8));
      gload_lds16(vb + (size_t)row * S_ + sc0 + col, (void*)(vbuf + seg * 8));
    }
    __syncthreads();
    int sl = wid * 64;   // each wave owns a 64-wide K slice of the chunk
#pragma unroll
    for (int kk = 0; kk < 64; kk += 32) {
      bf16x8 fa[4], fb[4];
#pragma unroll
      for (int m = 0; m < 4; ++m)
        fa[m] = *(const bf16x8*)(vbuf + (m * 16 + lr) * 256 + sl + kk + g * 8);
#pragma unroll
      for (int n = 0; n < 4; ++n)
        fb[n] = *(const bf16x8*)(kbuf + (n * 16 + lr) * 256 + sl + kk + g * 8);
#pragma unroll
      for (int m = 0; m < 4; ++m)
#pragma unroll
        for (int n = 0; n < 4; ++n)
          acc[m][n] = __builtin_amdgcn_mfma_f32_16x16x32_bf16(fa[m], fb[n], acc[m][n], 0, 0, 0);
    }
    __syncthreads();
  }

  // cross-wave reduce through LDS (reuse staging space)
  float* red = (float*)smem;   // 4 x [64][64] fp32 = 64KB
#pragma unroll
  for (int m = 0; m < 4; ++m)
#pragma unroll
    for (int n = 0; n < 4; ++n)
#pragma unroll
      for (int j = 0; j < 4; ++j)
        red[wid * 4096 + (m * 16 + g * 4 + j) * 64 + n * 16 + lr] = acc[m][n][j];
  __syncthreads();
  for (int idx = tid; idx < 4096; idx += 256) {
    float s = red[idx] + red[4096 + idx] + red[8192 + idx] + red[12288 + idx];
    vk[(size_t)bh * 4096 + idx] = (__bf16)s;
  }
}

// ---------------- ctx phase: out[b,s,h*64+d] = sum_e q[s,e]*vk[d,e] ----------------
__global__ __launch_bounds__(256) void ctx_gemm(const __bf16* __restrict__ qn,
                                                const __bf16* __restrict__ vk,
                                                float* __restrict__ out) {
  __shared__ __align__(16) __bf16 qbuf[128 * 64];
  __shared__ __align__(16) __bf16 wbuf[64 * 64];

  int st = blockIdx.x;   // s-tile (16)
  int bh = blockIdx.y;   // 128
  int b = bh >> 4, h = bh & 15;
  int tid = threadIdx.x, lane = tid & 63, wid = tid >> 6;
  int g = lane >> 4, lr = lane & 15;
  int s0 = st * 128;

#pragma unroll
  for (int it = 0; it < 4; ++it) {
    int seg = tid + it * 256;
    int row = seg >> 3, col = (seg & 7) * 8;
    gload_lds16(qn + (size_t)(b * S_ + s0 + row) * HID_ + h * DH_ + col,
                (void*)(qbuf + seg * 8));
  }
#pragma unroll
  for (int it = 0; it < 2; ++it) {
    int seg = tid + it * 256;
    gload_lds16(vk + (size_t)bh * 4096 + seg * 8, (void*)(wbuf + seg * 8));
  }
  __syncthreads();

  f32x4 acc[2][4] = {};
#pragma unroll
  for (int kk = 0; kk < 64; kk += 32) {
    bf16x8 fa[2], fb[4];
#pragma unroll
    for (int m = 0; m < 2; ++m)
      fa[m] = *(const bf16x8*)(qbuf + (wid * 32 + m * 16 + lr) * 64 + kk + g * 8);
#pragma unroll
    for (int n = 0; n < 4; ++n)
      fb[n] = *(const bf16x8*)(wbuf + (n * 16 + lr) * 64 + kk + g * 8);
#pragma unroll
    for (int m = 0; m < 2; ++m)
#pragma unroll
      for (int n = 0; n < 4; ++n)
        acc[m][n] = __builtin_amdgcn_mfma_f32_16x16x32_bf16(fa[m], fb[n], acc[m][n], 0, 0, 0);
  }

#pragma unroll
  for (int m = 0; m < 2; ++m) {
    int rbase = s0 + wid * 32 + m * 16 + g * 4;
#pragma unroll
    for (int n = 0; n < 4; ++n) {
      int d = n * 16 + lr;
#pragma unroll
      for (int j = 0; j < 4; ++j)
        out[(size_t)(b * S_ + rbase + j) * HID_ + h * DH_ + d] = acc[m][n][j];
    }
  }
}

extern "C" void kernel_launch(void* const* d_in, const int* in_sizes, int n_in,
                              void* d_out, int out_size, void* d_ws, size_t ws_size,
                              hipStream_t stream) {
  const float* hs   = (const float*)d_in[0];
  const int*   mask = (const int*)d_in[1];
  const float* Wq   = (const float*)d_in[2];
  const float* bq   = (const float*)d_in[3];
  const float* Wk   = (const float*)d_in[4];
  const float* bk   = (const float*)d_in[5];
  const float* Wv   = (const float*)d_in[6];
  const float* bv   = (const float*)d_in[7];
  float* out = (float*)d_out;

  // ws layout (bytes): needs ~137.1 MB total
  char* ws = (char*)d_ws;
  __bf16* hsb    = (__bf16*)(ws);                           // 32 MB
  __bf16* Wt     = (__bf16*)(ws + (33554432));              // 6 MB
  __bf16* qn     = (__bf16*)(ws + (41943040));              // 32 MB
  __bf16* kT     = (__bf16*)(ws + (75497472));              // 32 MB
  __bf16* vT     = (__bf16*)(ws + (109051904));             // 32 MB
  __bf16* vk     = (__bf16*)(ws + (142606336));             // 1 MB
  float*  validf = (float*)(ws + (143654912));              // 64 KB
  float*  counts = (float*)(ws + (143654912) + 65536);      // 32 B

  cast_hs<<<2048, 256, 0, stream>>>(hs, hsb, (B_ * S_ * HID_) / 8);
  transpose_w<<<dim3(32, 32, 3), dim3(32, 8), 0, stream>>>(Wq, Wk, Wv, Wt);
  mask_prep<<<8, 256, 0, stream>>>(mask, validf, counts);
  qkv_gemm8<<<768, 512, 0, stream>>>(hsb, Wt, bq, bk, bv, validf, counts, qn, kT, vT);
  kv_gemm<<<128, 256, 0, stream>>>(kT, vT, vk);
  ctx_gemm<<<dim3(16, 128), 256, 0, stream>>>(qn, vk, out);
}

// Round 3
// 184.890 us; speedup vs baseline: 1.2683x; 1.1278x over previous
//
#include <hip/hip_runtime.h>
#include <stdint.h>

// Problem constants
#define B_    8
#define S_    2048
#define HID_  1024
#define H_    16
#define DH_   64
#define M_    (B_ * S_)   // 16384 rows

using bf16x8 = __attribute__((ext_vector_type(8))) __bf16;
using bf16x4 = __attribute__((ext_vector_type(4))) __bf16;
using f32x4  = __attribute__((ext_vector_type(4))) float;

__device__ __forceinline__ void gload_lds16(const void* g, void* l) {
  __builtin_amdgcn_global_load_lds(
      (const __attribute__((address_space(1))) void*)g,
      (__attribute__((address_space(3))) void*)l, 16, 0, 0);
}

// ---------------- prep: cast hidden_states fp32 -> bf16 ----------------
__global__ void cast_hs(const float* __restrict__ hs, __bf16* __restrict__ out, int n8) {
  int i = blockIdx.x * blockDim.x + threadIdx.x;
  int stride = gridDim.x * blockDim.x;
  for (; i < n8; i += stride) {
    const float4* p = (const float4*)(hs + (size_t)i * 8);
    float4 a = p[0], c = p[1];
    bf16x8 v;
    v[0] = (__bf16)a.x; v[1] = (__bf16)a.y; v[2] = (__bf16)a.z; v[3] = (__bf16)a.w;
    v[4] = (__bf16)c.x; v[5] = (__bf16)c.y; v[6] = (__bf16)c.z; v[7] = (__bf16)c.w;
    *(bf16x8*)(out + (size_t)i * 8) = v;
  }
}

// ---------------- prep: W [k][n] -> Wt [w][n][k] bf16 ----------------
__global__ void transpose_w(const float* __restrict__ Wq, const float* __restrict__ Wk,
                            const float* __restrict__ Wv, __bf16* __restrict__ Wt) {
  __shared__ float tile[32][33];
  int w = blockIdx.z;
  const float* W = (w == 0) ? Wq : (w == 1) ? Wk : Wv;
  int k0 = blockIdx.x * 32, n0 = blockIdx.y * 32;
  int tx = threadIdx.x, ty = threadIdx.y;
#pragma unroll
  for (int i = 0; i < 4; ++i)
    tile[ty * 4 + i][tx] = W[(size_t)(k0 + ty * 4 + i) * HID_ + n0 + tx];
  __syncthreads();
#pragma unroll
  for (int i = 0; i < 4; ++i)
    Wt[(size_t)w * HID_ * HID_ + (size_t)(n0 + ty * 4 + i) * HID_ + k0 + tx] =
        (__bf16)tile[tx][ty * 4 + i];
}

// ---------------- prep: per-row validity + per-batch count ----------------
__global__ void mask_prep(const int* __restrict__ mask, float* __restrict__ validf,
                          float* __restrict__ counts) {
  __shared__ float red[256];
  int b = blockIdx.x;
  float cnt = 0.f;
  for (int s = threadIdx.x; s < S_; s += 256) {
    float v = (mask[b * S_ + s] == 0) ? 1.f : 0.f;
    validf[b * S_ + s] = v;
    cnt += v;
  }
  red[threadIdx.x] = cnt;
  __syncthreads();
  for (int off = 128; off > 0; off >>= 1) {
    if (threadIdx.x < off) red[threadIdx.x] += red[threadIdx.x + off];
    __syncthreads();
  }
  if (threadIdx.x == 0) counts[b] = red[0];
}

// ============ QKV GEMM: 256x256 tile, BK=64, 8-wave, pipelined K-step =======
// One vmcnt(0)+s_barrier per K-step; ds_reads front-loaded in pinned groups;
// MFMA clusters guarded by counted lgkmcnt (4/8/4/0) so waves drift within a
// step and LDS reads overlap MFMA across waves. T2 XOR-swizzle (0 conflicts),
// T5 setprio around clusters. B-frags read once per kk (24 reads/step).
// Reg budget: acc 128 + frags 64 (fb,fbN,fa0,fa1) + misc ~ <=256 -> 2 w/SIMD.
__global__ __launch_bounds__(512, 2) void qkv_gemm8(
    const __bf16* __restrict__ hsb, const __bf16* __restrict__ Wt,
    const float* __restrict__ biasq, const float* __restrict__ biask,
    const float* __restrict__ biasv, const float* __restrict__ validf,
    const float* __restrict__ counts, __bf16* __restrict__ qn,
    __bf16* __restrict__ kT, __bf16* __restrict__ vT) {
  __shared__ __bf16 As[2][2][128 * 64];   // [dbuf][m-half][row*64+col]
  __shared__ __bf16 Bs[2][2][128 * 64];   // [dbuf][n-half][row*64+col]

  // XCD-aware block order: each XCD gets 8 consecutive tm x all 12 (tn,w).
  int bid = blockIdx.x;
  int swz = (bid & 7) * 96 + (bid >> 3);       // 768 % 8 == 0 -> bijective
  int tm = swz / 12;
  int tnw = swz - tm * 12;
  int tn = tnw & 3;
  int w  = tnw >> 2;

  int tid = threadIdx.x;
  int lane = tid & 63, wid = tid >> 6;
  int lr = lane & 15, g = lane >> 4;
  int wr = wid >> 2, wcn = wid & 3;

  int m0 = tm * 256, n0 = tn * 256;
  const __bf16* Bsrc = Wt + (size_t)w * (HID_ * HID_);

  // staging constants (512 threads stage one 128x64 half = 2 x 16B each)
  int srow = tid >> 3;                              // row 0..63 (+64 for seg 1)
  int scol = ((tid & 7) ^ (srow & 7)) << 3;         // swizzled source col (elems)
  int soff = tid * 16;                              // LDS byte offset (+8192 seg 1)

  auto stA = [&](int t_, int ah) {
    const __bf16* s0 = hsb + (size_t)(m0 + ah * 128 + srow) * HID_ + t_ * 64 + scol;
    char* d = (char*)&As[t_ & 1][ah][0] + soff;
    gload_lds16(s0, d);
    gload_lds16(s0 + (size_t)64 * HID_, d + 8192);
  };
  auto stB = [&](int t_, int bh) {
    const __bf16* s0 = Bsrc + (size_t)(n0 + bh * 128 + srow) * HID_ + t_ * 64 + scol;
    char* d = (char*)&Bs[t_ & 1][bh][0] + soff;
    gload_lds16(s0, d);
    gload_lds16(s0 + (size_t)64 * HID_, d + 8192);
  };

  // ds_read constants
  int swz8 = (lr & 7) << 4;
  int arow = wr * 64 + lr;          // + mf*16
  int brow = (wcn & 1) * 64 + lr;   // + nf*16
  int bsel = wcn >> 1;

  f32x4 acc[8][4] = {};
  bf16x8 fb[4], fbN[4], fa0[4], fa1[4];

#define RD_A(DST, BUF, MH, KK)                                                \
  _Pragma("unroll")                                                           \
  for (int mf = 0; mf < 4; ++mf)                                              \
    DST[mf] = *(const bf16x8*)((const char*)&As[BUF][MH][0] +                 \
                               (arow + mf * 16) * 128 +                       \
                               (((KK) * 64 + g * 16) ^ swz8));                \
  __builtin_amdgcn_sched_barrier(0);

#define RD_B(DST, BUF, KK)                                                    \
  _Pragma("unroll")                                                           \
  for (int nf = 0; nf < 4; ++nf)                                              \
    DST[nf] = *(const bf16x8*)((const char*)&Bs[BUF][bsel][0] +               \
                               (brow + nf * 16) * 128 +                       \
                               (((KK) * 64 + g * 16) ^ swz8));                \
  __builtin_amdgcn_sched_barrier(0);

#define CLUSTER(ACCB, FA, FB, LG)                                             \
  asm volatile("s_waitcnt lgkmcnt(" #LG ")" ::: "memory");                    \
  __builtin_amdgcn_sched_barrier(0);                                          \
  __builtin_amdgcn_s_setprio(1);                                              \
  _Pragma("unroll")                                                           \
  for (int mf = 0; mf < 4; ++mf)                                              \
    _Pragma("unroll")                                                         \
    for (int nf = 0; nf < 4; ++nf)                                            \
      acc[(ACCB) + mf][nf] = __builtin_amdgcn_mfma_f32_16x16x32_bf16(         \
          FA[mf], FB[nf], acc[(ACCB) + mf][nf], 0, 0, 0);                     \
  __builtin_amdgcn_s_setprio(0);                                              \
  __builtin_amdgcn_sched_barrier(0);

  // prologue: stage tile 0 into buf 0
  stA(0, 0); stA(0, 1); stB(0, 0); stB(0, 1);

#pragma unroll 2
  for (int t = 0; t < 16; ++t) {
    int buf = t & 1;
    // tile t staged (issued during t-1); all reads of t-1 complete (their
    // lgkm(0) preceded each wave's last MFMA cluster of t-1).
    asm volatile("s_waitcnt vmcnt(0)" ::: "memory");
    __builtin_amdgcn_s_barrier();
    __builtin_amdgcn_sched_barrier(0);

    // front-loaded reads, pinned group order (12 outstanding after this):
    RD_B(fb,  buf, 0);        // G1: oldest 4
    RD_A(fa0, buf, 0, 0);     // G2
    RD_A(fa1, buf, 1, 0);     // G3
    if (t < 15) { stA(t + 1, 0); stA(t + 1, 1); }

    CLUSTER(0, fa0, fb, 4)    // needs G1,G2 (8 oldest) -> lgkm(4)

    RD_B(fbN, buf, 1);        // G4
    RD_A(fa0, buf, 0, 1);     // G5 (reuse fa0 regs)
    if (t < 15) stB(t + 1, 0);

    CLUSTER(4, fa1, fb, 8)    // needs G3 done; G4,G5 outstanding -> lgkm(8)

    RD_A(fa1, buf, 1, 1);     // G6 (reuse fa1 regs)
    if (t < 15) stB(t + 1, 1);

    CLUSTER(0, fa0, fbN, 4)   // needs G4,G5; G6 outstanding -> lgkm(4)
    CLUSTER(4, fa1, fbN, 0)   // needs G6 -> lgkm(0)
  }
#undef RD_A
#undef RD_B
#undef CLUSTER

  // ---- fused epilogue ----
  const float* bias = (w == 0) ? biasq : (w == 1) ? biask : biasv;
  float bb[4];
#pragma unroll
  for (int nf = 0; nf < 4; ++nf) bb[nf] = bias[n0 + wcn * 64 + nf * 16 + lr];

  int batch = m0 >> 11;              // 256-row tile never crosses batch (2048 rows)
  float invcnt = 1.0f / counts[batch];
  int h = tn * 4 + wcn;              // head owned by this wave

#pragma unroll
  for (int m = 0; m < 8; ++m) {
    int mh = m >> 2, mf = m & 3;
    int rbase = m0 + mh * 128 + wr * 64 + mf * 16 + g * 4;
    float vld[4];
#pragma unroll
    for (int j = 0; j < 4; ++j) vld[j] = validf[rbase + j];
    float ss[4] = {0.f, 0.f, 0.f, 0.f};
#pragma unroll
    for (int nf = 0; nf < 4; ++nf)
#pragma unroll
      for (int j = 0; j < 4; ++j) {
        float x = (acc[m][nf][j] + bb[nf]) * vld[j];
        acc[m][nf][j] = x;
        ss[j] += x * x;
      }
    float sc[4];
#pragma unroll
    for (int j = 0; j < 4; ++j) {
      float s = ss[j];
      s += __shfl_xor(s, 1);
      s += __shfl_xor(s, 2);
      s += __shfl_xor(s, 4);
      s += __shfl_xor(s, 8);   // reduce over 16 lanes holding this row's 64 cols
      if (w == 2) sc[j] = vld[j] * invcnt;
      else        sc[j] = 1.0f / fmaxf(sqrtf(s), 1e-12f);
    }
    if (w == 0) {
#pragma unroll
      for (int nf = 0; nf < 4; ++nf) {
        int c = n0 + wcn * 64 + nf * 16 + lr;
#pragma unroll
        for (int j = 0; j < 4; ++j)
          qn[(size_t)(rbase + j) * HID_ + c] = (__bf16)(acc[m][nf][j] * sc[j]);
      }
    } else {
      __bf16* dst = (w == 1) ? kT : vT;
      int sbase = rbase & (S_ - 1);
#pragma unroll
      for (int nf = 0; nf < 4; ++nf) {
        int d = nf * 16 + lr;
        bf16x4 pk;
#pragma unroll
        for (int j = 0; j < 4; ++j) pk[j] = (__bf16)(acc[m][nf][j] * sc[j]);
        *(bf16x4*)(dst + (size_t)((batch * H_ + h) * DH_ + d) * S_ + sbase) = pk;
      }
    }
  }
}

// ---------------- kv phase: vk[bh][d][e] = sum_s v[s,d]*k[s,e] ----------------
__global__ __launch_bounds__(256) void kv_gemm(const __bf16* __restrict__ kT,
                                               const __bf16* __restrict__ vT,
                                               __bf16* __restrict__ vk) {
  __shared__ __align__(16) char smem[65536];
  __bf16* kbuf = (__bf16*)smem;              // [64][256]
  __bf16* vbuf = (__bf16*)(smem + 32768);    // [64][256]

  int bh = blockIdx.x;
  int tid = threadIdx.x, lane = tid & 63, wid = tid >> 6;
  int g = lane >> 4, lr = lane & 15;
  const __bf16* kb = kT + (size_t)bh * DH_ * S_;
  const __bf16* vb = vT + (size_t)bh * DH_ * S_;

  f32x4 acc[4][4] = {};

  for (int sc0 = 0; sc0 < S_; sc0 += 256) {
#pragma unroll
    for (int it = 0; it < 8; ++it) {
      int seg = tid + it * 256;
      int row = seg >> 5, col = (seg & 31) * 8;
      gload_lds16(kb + (size_t)row * S_ + sc0 + col, (void*)(kbuf + seg * 8));
      gload_lds16(vb + (size_t)row * S_ + sc0 + col, (void*)(vbuf + seg * 8));
    }
    __syncthreads();
    int sl = wid * 64;   // each wave owns a 64-wide K slice of the chunk
#pragma unroll
    for (int kk = 0; kk < 64; kk += 32) {
      bf16x8 fa[4], fb[4];
#pragma unroll
      for (int m = 0; m < 4; ++m)
        fa[m] = *(const bf16x8*)(vbuf + (m * 16 + lr) * 256 + sl + kk + g * 8);
#pragma unroll
      for (int n = 0; n < 4; ++n)
        fb[n] = *(const bf16x8*)(kbuf + (n * 16 + lr) * 256 + sl + kk + g * 8);
#pragma unroll
      for (int m = 0; m < 4; ++m)
#pragma unroll
        for (int n = 0; n < 4; ++n)
          acc[m][n] = __builtin_amdgcn_mfma_f32_16x16x32_bf16(fa[m], fb[n], acc[m][n], 0, 0, 0);
    }
    __syncthreads();
  }

  // cross-wave reduce through LDS (reuse staging space)
  float* red = (float*)smem;   // 4 x [64][64] fp32 = 64KB
#pragma unroll
  for (int m = 0; m < 4; ++m)
#pragma unroll
    for (int n = 0; n < 4; ++n)
#pragma unroll
      for (int j = 0; j < 4; ++j)
        red[wid * 4096 + (m * 16 + g * 4 + j) * 64 + n * 16 + lr] = acc[m][n][j];
  __syncthreads();
  for (int idx = tid; idx < 4096; idx += 256) {
    float s = red[idx] + red[4096 + idx] + red[8192 + idx] + red[12288 + idx];
    vk[(size_t)bh * 4096 + idx] = (__bf16)s;
  }
}

// ---------------- ctx phase: out[b,s,h*64+d] = sum_e q[s,e]*vk[d,e] ----------------
__global__ __launch_bounds__(256) void ctx_gemm(const __bf16* __restrict__ qn,
                                                const __bf16* __restrict__ vk,
                                                float* __restrict__ out) {
  __shared__ __align__(16) __bf16 qbuf[128 * 64];
  __shared__ __align__(16) __bf16 wbuf[64 * 64];

  int st = blockIdx.x;   // s-tile (16)
  int bh = blockIdx.y;   // 128
  int b = bh >> 4, h = bh & 15;
  int tid = threadIdx.x, lane = tid & 63, wid = tid >> 6;
  int g = lane >> 4, lr = lane & 15;
  int s0 = st * 128;

#pragma unroll
  for (int it = 0; it < 4; ++it) {
    int seg = tid + it * 256;
    int row = seg >> 3, col = (seg & 7) * 8;
    gload_lds16(qn + (size_t)(b * S_ + s0 + row) * HID_ + h * DH_ + col,
                (void*)(qbuf + seg * 8));
  }
#pragma unroll
  for (int it = 0; it < 2; ++it) {
    int seg = tid + it * 256;
    gload_lds16(vk + (size_t)bh * 4096 + seg * 8, (void*)(wbuf + seg * 8));
  }
  __syncthreads();

  f32x4 acc[2][4] = {};
#pragma unroll
  for (int kk = 0; kk < 64; kk += 32) {
    bf16x8 fa[2], fb[4];
#pragma unroll
    for (int m = 0; m < 2; ++m)
      fa[m] = *(const bf16x8*)(qbuf + (wid * 32 + m * 16 + lr) * 64 + kk + g * 8);
#pragma unroll
    for (int n = 0; n < 4; ++n)
      fb[n] = *(const bf16x8*)(wbuf + (n * 16 + lr) * 64 + kk + g * 8);
#pragma unroll
    for (int m = 0; m < 2; ++m)
#pragma unroll
      for (int n = 0; n < 4; ++n)
        acc[m][n] = __builtin_amdgcn_mfma_f32_16x16x32_bf16(fa[m], fb[n], acc[m][n], 0, 0, 0);
  }

#pragma unroll
  for (int m = 0; m < 2; ++m) {
    int rbase = s0 + wid * 32 + m * 16 + g * 4;
#pragma unroll
    for (int n = 0; n < 4; ++n) {
      int d = n * 16 + lr;
#pragma unroll
      for (int j = 0; j < 4; ++j)
        out[(size_t)(b * S_ + rbase + j) * HID_ + h * DH_ + d] = acc[m][n][j];
    }
  }
}

extern "C" void kernel_launch(void* const* d_in, const int* in_sizes, int n_in,
                              void* d_out, int out_size, void* d_ws, size_t ws_size,
                              hipStream_t stream) {
  const float* hs   = (const float*)d_in[0];
  const int*   mask = (const int*)d_in[1];
  const float* Wq   = (const float*)d_in[2];
  const float* bq   = (const float*)d_in[3];
  const float* Wk   = (const float*)d_in[4];
  const float* bk   = (const float*)d_in[5];
  const float* Wv   = (const float*)d_in[6];
  const float* bv   = (const float*)d_in[7];
  float* out = (float*)d_out;

  // ws layout (bytes): needs ~137.1 MB total
  char* ws = (char*)d_ws;
  __bf16* hsb    = (__bf16*)(ws);                           // 32 MB
  __bf16* Wt     = (__bf16*)(ws + (33554432));              // 6 MB
  __bf16* qn     = (__bf16*)(ws + (41943040));              // 32 MB
  __bf16* kT     = (__bf16*)(ws + (75497472));              // 32 MB
  __bf16* vT     = (__bf16*)(ws + (109051904));             // 32 MB
  __bf16* vk     = (__bf16*)(ws + (142606336));             // 1 MB
  float*  validf = (float*)(ws + (143654912));              // 64 KB
  float*  counts = (float*)(ws + (143654912) + 65536);      // 32 B

  cast_hs<<<2048, 256, 0, stream>>>(hs, hsb, (B_ * S_ * HID_) / 8);
  transpose_w<<<dim3(32, 32, 3), dim3(32, 8), 0, stream>>>(Wq, Wk, Wv, Wt);
  mask_prep<<<8, 256, 0, stream>>>(mask, validf, counts);
  qkv_gemm8<<<768, 512, 0, stream>>>(hsb, Wt, bq, bk, bv, validf, counts, qn, kT, vT);
  kv_gemm<<<128, 256, 0, stream>>>(kT, vT, vk);
  ctx_gemm<<<dim3(16, 128), 256, 0, stream>>>(qn, vk, out);
}